// Round 9
// baseline (5861.150 us; speedup 1.0000x reference)
//
#include <hip/hip_runtime.h>
#include <math.h>

#define B_ 64
#define T_ 2048
#define D_ 512
#define BT_ (B_ * T_)   // 131072
#define XWORDS (B_ * D_)   // 32768 8-byte words per parity slot: [batch][512]

typedef unsigned long long u64;

// ---------------------------------------------------------------------------
// Kernel 1: weight prep (transpose to k-major for coalesced GEMM/GEMV reads)
// ---------------------------------------------------------------------------
__global__ void prep_weights(const float* __restrict__ tau_w,
                             const float* __restrict__ mem_w,
                             float* __restrict__ Wcat,
                             float* __restrict__ WTh) {
    int idx = blockIdx.x * 256 + threadIdx.x;   // 0 .. 524287
    {
        int k = idx >> 10, j = idx & 1023;
        float v = (j < 512) ? tau_w[j * 1024 + k] : mem_w[(j - 512) * 512 + k];
        Wcat[idx] = v;
    }
    if (idx < 512 * 512) {
        int k = idx >> 9, d = idx & 511;
        WTh[idx] = tau_w[d * 1024 + 512 + k];
    }
}

// ---------------------------------------------------------------------------
// Kernel 2: f32 GEMM  C[131072][1024] = X[131072][512] @ Wcat[512][1024] + bias
// ---------------------------------------------------------------------------
__global__ __launch_bounds__(256, 2)
void gemm_xw(const float* __restrict__ X, const float* __restrict__ Wc,
             const float* __restrict__ tau_b, const float* __restrict__ mem_b,
             float* __restrict__ Aout, float* __restrict__ Mout) {
    __shared__ __align__(16) float As[16][128];  // [k][m]
    __shared__ __align__(16) float Bs[16][128];  // [k][n]
    const int bn = blockIdx.x;          // 0..7
    const int bm = blockIdx.y;          // 0..1023
    const int tid = threadIdx.x;
    const int tm = (tid >> 4) << 3;
    const int tn = (tid & 15) << 3;
    const int m0 = bm * 128, n0 = bn * 128;

    const float4* X4 = (const float4*)X;
    const float4* Wc4 = (const float4*)Wc;

    float acc[8][8];
#pragma unroll
    for (int i = 0; i < 8; i++)
#pragma unroll
        for (int j = 0; j < 8; j++) acc[i][j] = 0.0f;

    const int ar = tid >> 1;              // 0..127 row in tile
    const int ac2 = (tid & 1) * 2;        // float4 col 0 or 2
    const int bkr = tid >> 4;             // 0..15
    const int bc = (tid & 15) * 2;        // float4 col 0..30

    for (int kt = 0; kt < 512; kt += 16) {
        float4 av0 = X4[(m0 + ar) * 128 + (kt >> 2) + ac2];
        float4 av1 = X4[(m0 + ar) * 128 + (kt >> 2) + ac2 + 1];
        float4 bv0 = Wc4[(kt + bkr) * 256 + bn * 32 + bc];
        float4 bv1 = Wc4[(kt + bkr) * 256 + bn * 32 + bc + 1];
        __syncthreads();   // protect previous iteration's reads
        As[ac2 * 4 + 0][ar] = av0.x;
        As[ac2 * 4 + 1][ar] = av0.y;
        As[ac2 * 4 + 2][ar] = av0.z;
        As[ac2 * 4 + 3][ar] = av0.w;
        As[ac2 * 4 + 4][ar] = av1.x;
        As[ac2 * 4 + 5][ar] = av1.y;
        As[ac2 * 4 + 6][ar] = av1.z;
        As[ac2 * 4 + 7][ar] = av1.w;
        *(float4*)&Bs[bkr][bc * 4] = bv0;
        *(float4*)&Bs[bkr][bc * 4 + 4] = bv1;
        __syncthreads();
#pragma unroll
        for (int kk = 0; kk < 16; kk++) {
            float4 a0 = *(const float4*)&As[kk][tm];
            float4 a1 = *(const float4*)&As[kk][tm + 4];
            float4 b0 = *(const float4*)&Bs[kk][tn];
            float4 b1 = *(const float4*)&Bs[kk][tn + 4];
            float av[8] = {a0.x, a0.y, a0.z, a0.w, a1.x, a1.y, a1.z, a1.w};
            float bv[8] = {b0.x, b0.y, b0.z, b0.w, b1.x, b1.y, b1.z, b1.w};
#pragma unroll
            for (int i = 0; i < 8; i++)
#pragma unroll
                for (int j = 0; j < 8; j++)
                    acc[i][j] = fmaf(av[i], bv[j], acc[i][j]);
        }
    }

    const bool isA = (bn < 4);
    float* Cout = isA ? Aout : Mout;
    const float* bias = isA ? tau_b : mem_b;
    const int ncol0 = (isA ? n0 : n0 - 512) + tn;
    float bj[8];
#pragma unroll
    for (int j = 0; j < 8; j++) bj[j] = bias[ncol0 + j];
#pragma unroll
    for (int i = 0; i < 8; i++) {
        size_t off = (size_t)(m0 + tm + i) * 512 + ncol0;
        float4 o0, o1;
        o0.x = acc[i][0] + bj[0]; o0.y = acc[i][1] + bj[1];
        o0.z = acc[i][2] + bj[2]; o0.w = acc[i][3] + bj[3];
        o1.x = acc[i][4] + bj[4]; o1.y = acc[i][5] + bj[5];
        o1.z = acc[i][6] + bj[6]; o1.w = acc[i][7] + bj[7];
        *(float4*)&Cout[off] = o0;
        *(float4*)&Cout[off + 4] = o1;
    }
}

// ---------------------------------------------------------------------------
// Kernel 3: reset sync state every launch (graph-replay safe).
// Slot0 words = {seq=0, tau=1.0} (the t=0 carry); slot1 words = {seq=0, *}.
// ---------------------------------------------------------------------------
__global__ void init_sync(u64* __restrict__ xchg, int* __restrict__ ctr) {
    int idx = blockIdx.x * 256 + threadIdx.x;   // 0 .. 65535
    if (idx < 2 * XWORDS) xchg[idx] = (idx < XWORDS) ? 0x3F800000ull : 0ull;
    if (idx < 16) ctr[idx] = 0;
}

// ---------------------------------------------------------------------------
// Kernel 4: cooperative scan — register-resident weights + readlane broadcast.
//
// Round-8 finding: per-step 128KB LDS weight re-read (256 ds_read_b128/CU
// ~ 3000 cyc on the shared LDS pipe) was the bottleneck. Round-9 mapping
// makes the per-lane weight slice fit registers: lane = channel (64 lanes =
// block's 64 channels), wave ws = k-window [ws*64, ws*64+64). Per lane:
// 64 loop-invariant floats (16 float4) — NO asm pins (rounds 2-5 lesson
// inverted: the pins' vector-tuple constraints plausibly CAUSED the spills;
// clean named locals + waves_per_eu(2,2) get a 256-reg budget).
//
// tau broadcast OFF the LDS pipe: after the poll, lane l holds tau[ws*64+l];
// v_readlane with unroll-constant index -> SGPR operand consumed directly by
// v_fma. Self-segment tau via tiny LDS buffer written by the epilogue.
// A/M global loads software-pipelined one step ahead (HBM latency hidden).
// 112KB referenced LDS pad forces 1 block/CU so the XCD-rank role mapping
// stays bijective (32 blocks/XCD).
// ---------------------------------------------------------------------------
__global__ __launch_bounds__(512)
__attribute__((amdgpu_waves_per_eu(2, 2)))
void scan_reg(const float* __restrict__ WTh,
              const float* __restrict__ Mm,
              const float* __restrict__ log_thresh,
              float* __restrict__ AmOut,   // A in / spikes out (d_out)
              float* __restrict__ OutTail, // d_out base for tau/v tails
              u64* __restrict__ xchg,
              int* __restrict__ ctr) {
    __shared__ __align__(16) float part[2][8][64];   // 4 KB
    __shared__ __align__(16) float tau_sm[2][64];    // 512 B (self segment)
    __shared__ int role_s;
    __shared__ float4 pad_lds[7168];                 // 112 KB: force 1 blk/CU

    const int tid = threadIdx.x;
    if (tid == 9999) ((volatile float*)pad_lds)[0] = 1.f;   // keep pad alive

    if (tid == 0) {
        unsigned xcd;
        asm volatile("s_getreg_b32 %0, hwreg(HW_REG_XCC_ID)" : "=s"(xcd));
        xcd &= 7;
        int rank = atomicAdd(&ctr[xcd], 1) & 31;
        role_s = ((rank & 7) << 8) | ((int)xcd * 4 + (rank >> 3));
    }
    __syncthreads();
    const int sg = role_s >> 8;    // channel segment 0..7
    const int bp = role_s & 255;   // batch pair 0..31

    const int ws = tid >> 6;       // wave = k-window [ws*64, ws*64+64)
    const int lane = tid & 63;     // lane = channel within segment
    const bool self = (ws == sg);

    // ---- loop-invariant weight fragment: 16 float4 = 64 VGPRs ----
    // w[q4][j] = WTh[(ws*64 + q4*4 + j)*512 + sg*64 + lane]
    const float* wcol = WTh + sg * 64 + lane;
    float4 w[16];
#pragma unroll
    for (int q4 = 0; q4 < 16; q4++) {
        const int k0 = ws * 64 + q4 * 4;
        w[q4].x = wcol[(size_t)(k0 + 0) * 512];
        w[q4].y = wcol[(size_t)(k0 + 1) * 512];
        w[q4].z = wcol[(size_t)(k0 + 2) * 512];
        w[q4].w = wcol[(size_t)(k0 + 3) * 512];
    }

    // epilogue identity (tid < 128): batch-in-pair eb, channel ech
    const int eb = tid >> 6;             // 0 or 1
    const int ech = tid & 63;
    const int gch = sg * 64 + ech;
    float thr = 0.f, v = 0.f, tau_keep = 0.f;
    if (tid < 128) thr = 1.0f / (1.0f + expf(-log_thresh[gch]));
    size_t abase = ((size_t)(bp * 2 + eb) * T_) * D_ + gch;

    if (tid < 128) tau_sm[eb][ech] = 1.0f;   // t=0 carry for self segment

    // prime the A/M software pipeline (step 1's values)
    float a_pf = 0.f, m_pf = 0.f;
    if (tid < 128) { a_pf = AmOut[abase]; m_pf = Mm[abase]; }
    __syncthreads();

    for (int c = 1; c <= T_; c++) {
        // issue next step's A/M loads (consumed next iteration's epilogue)
        float a_nx = 0.f, m_nx = 0.f;
        if (tid < 128) {
            size_t nx = (c < T_) ? abase + D_ : abase;
            a_nx = AmOut[nx]; m_nx = Mm[nx];
        }

        // ---- acquire this wave's tau segment (64 values, one per lane) ----
        float t0f, t1f;
        if (!self) {
            const u64* s0 = xchg + (size_t)((c - 1) & 1) * XWORDS
                                 + (size_t)(bp * 2) * 512 + ws * 64 + lane;
            const u64* s1 = s0 + 512;   // batch 1 of the pair
            const unsigned tgt = (unsigned)(c - 1);
            u64 v0, v1;
            int guard = 0;
            do {
                v0 = __hip_atomic_load(s0, __ATOMIC_RELAXED,
                                       __HIP_MEMORY_SCOPE_AGENT);
                v1 = __hip_atomic_load(s1, __ATOMIC_RELAXED,
                                       __HIP_MEMORY_SCOPE_AGENT);
            } while ((((unsigned)(v0 >> 32) < tgt) |
                      ((unsigned)(v1 >> 32) < tgt)) && ++guard < (1 << 22));
            t0f = __uint_as_float((unsigned)v0);
            t1f = __uint_as_float((unsigned)v1);
        } else {
            t0f = tau_sm[0][lane];      // written by prev step's epilogue
            t1f = tau_sm[1][lane];      // (ordered by barrier B)
        }
        const int t0i = __float_as_int(t0f);
        const int t1i = __float_as_int(t1f);

        // ---- FMA over own 64-k window: readlane broadcast, reg weights ----
        float acc0 = 0.f, acc1 = 0.f;
#pragma unroll
        for (int q4 = 0; q4 < 16; q4++) {
#pragma unroll
            for (int j = 0; j < 4; j++) {
                const int kk = q4 * 4 + j;
                const float wv = (j == 0) ? w[q4].x : (j == 1) ? w[q4].y
                               : (j == 2) ? w[q4].z : w[q4].w;
                float ta = __uint_as_float(
                    (unsigned)__builtin_amdgcn_readlane(t0i, kk));
                float tb = __uint_as_float(
                    (unsigned)__builtin_amdgcn_readlane(t1i, kk));
                acc0 = fmaf(ta, wv, acc0);
                acc1 = fmaf(tb, wv, acc1);
            }
        }
        part[0][ws][lane] = acc0;
        part[1][ws][lane] = acc1;
        __syncthreads();   // A: all 8 k-window partials ready

        // ---- epilogue on 128 threads; the store IS the publication ----
        if (tid < 128) {
            float sum = 0.f;
#pragma unroll
            for (int j = 0; j < 8; j++) sum += part[eb][j][ech];
            float pre = sum + a_pf;
            float tau = 1.0f / (1.0f + expf(-pre));
            float alpha = expf(-1.0f / (tau + 1e-6f));
            v = alpha * v + (1.0f - alpha) * m_pf;
            float s = (v >= thr) ? 1.0f : 0.0f;
            AmOut[abase] = s;            // overwrite A slot with spike
            v = v * (1.0f - s);
            tau_keep = tau;
            tau_sm[eb][ech] = tau;       // self-segment shortcut
            u64 pack = ((u64)(unsigned)c << 32) | (u64)__float_as_uint(tau);
            __hip_atomic_store(&xchg[(size_t)(c & 1) * XWORDS
                                     + (bp * 2 + eb) * 512 + gch],
                               pack, __ATOMIC_RELAXED, __HIP_MEMORY_SCOPE_AGENT);
            abase += D_;
            a_pf = a_nx; m_pf = m_nx;    // advance the pipeline
        }
        __syncthreads();   // B: part[] reusable, tau_sm visible to wave sg
    }

    if (tid < 128) {
        const size_t batch = bp * 2 + eb;
        OutTail[(size_t)BT_ * D_ + batch * D_ + gch] = tau_keep;
        OutTail[(size_t)BT_ * D_ + (size_t)B_ * D_ + batch * D_ + gch] = v;
    }
}

// ---------------------------------------------------------------------------
extern "C" void kernel_launch(void* const* d_in, const int* in_sizes, int n_in,
                              void* d_out, int out_size, void* d_ws, size_t ws_size,
                              hipStream_t stream) {
    (void)in_sizes; (void)n_in; (void)out_size; (void)ws_size;
    const float* x          = (const float*)d_in[0];
    const float* tau_w      = (const float*)d_in[1];
    const float* tau_b      = (const float*)d_in[2];
    const float* mem_w      = (const float*)d_in[3];
    const float* mem_b      = (const float*)d_in[4];
    const float* log_thresh = (const float*)d_in[5];
    float* out = (float*)d_out;

    // workspace layout
    float* Wcat = (float*)d_ws;            // 512*1024 (dead after GEMM)
    float* WTh  = Wcat + 512 * 1024;       // 512*512
    float* Mout = WTh + 512 * 512;         // 131072*512
    // sync state reuses the Wcat region (GEMM finishes before init_sync)
    u64* xchg = (u64*)d_ws;                           // 2*XWORDS*8 = 512 KB
    int* ctr  = (int*)((char*)d_ws + 2 * XWORDS * sizeof(u64));

    float* Aout = out;                     // spikes region doubles as A buffer

    prep_weights<<<2048, 256, 0, stream>>>(tau_w, mem_w, Wcat, WTh);
    gemm_xw<<<dim3(8, 1024), 256, 0, stream>>>(x, Wcat, tau_b, mem_b, Aout, Mout);
    init_sync<<<256, 256, 0, stream>>>(xchg, ctr);

    const float* WThc = WTh;
    const float* Mmc  = Mout;
    const float* ltc  = log_thresh;
    float* outp = out;
    u64* xchgp = xchg;
    int* ctrp = ctr;
    void* args[7] = {(void*)&WThc, (void*)&Mmc, (void*)&ltc,
                     (void*)&Aout, (void*)&outp, (void*)&xchgp, (void*)&ctrp};
    hipLaunchCooperativeKernel((const void*)scan_reg, dim3(256), dim3(512),
                               args, 0, stream);
}